// Round 6
// baseline (321.795 us; speedup 1.0000x reference)
//
#include <hip/hip_runtime.h>

typedef float f32x4 __attribute__((ext_vector_type(4)));
typedef short s16x8 __attribute__((ext_vector_type(8)));
typedef unsigned short u16;

#define NB 8
#define SEQ 1024
#define CIN 512
#define NH 8
#define DK 64
#define MROWS (NB*SEQ)

__device__ __forceinline__ u16 bf16_of(float f) {
  unsigned u = __builtin_bit_cast(unsigned, f);
  u += 0x7fffu + ((u >> 16) & 1u);           // RTNE
  return (u16)(u >> 16);
}
__device__ __forceinline__ float f32_of(u16 b) {
  unsigned u = ((unsigned)b) << 16;
  return __builtin_bit_cast(float, u);
}

// ---------------- QKV projection: Y = X W^T + b  (bf16 MFMA, X split hi/lo) ----------------
// All outputs transposed to head-major: q/k -> [n][h][tok][d], v -> [n][h][d][tok]
#define BM 128
#define BN 128
#define BK 32
#define LDP 40    // staging row pad (u16)
#define TP  136   // transpose buffer row pad (u16)

__global__ __launch_bounds__(256, 2)
void proj_kernel(const float* __restrict__ x,
                 const float* __restrict__ wq, const float* __restrict__ bq,
                 const float* __restrict__ wk, const float* __restrict__ bk,
                 const float* __restrict__ wv, const float* __restrict__ bv,
                 u16* __restrict__ qht, u16* __restrict__ qlt,
                 u16* __restrict__ kt_, u16* __restrict__ vt_)
{
  __shared__ __align__(16) u16 smem[128 * TP];
  u16 (*Ah)[LDP] = (u16(*)[LDP])(smem);
  u16 (*Al)[LDP] = (u16(*)[LDP])(smem + 128*LDP);
  u16 (*Bw)[LDP] = (u16(*)[LDP])(smem + 256*LDP);

  const int tid  = threadIdx.x;
  const int wid  = tid >> 6, lane = tid & 63;
  const int g    = lane >> 4, li  = lane & 15;
  const int m0   = blockIdx.x * BM;
  const int n0   = blockIdx.y * BN;
  const int z    = blockIdx.z;

  const float* w    = (z == 0) ? wq : (z == 1) ? wk : wv;
  const float* bias = (z == 0) ? bq : (z == 1) ? bk : bv;

  const int wm = wid >> 1, wn = wid & 1;

  f32x4 acc[4][4];
  #pragma unroll
  for (int i = 0; i < 4; i++)
    #pragma unroll
    for (int j = 0; j < 4; j++)
      acc[i][j] = f32x4{0.f, 0.f, 0.f, 0.f};

  const int srow  = tid >> 1;
  const int shalf = (tid & 1) * 16;

  for (int k0 = 0; k0 < CIN; k0 += BK) {
    __syncthreads();
    {
      const float* ax = x + (size_t)(m0 + srow) * CIN + k0 + shalf;
      #pragma unroll
      for (int e = 0; e < 16; e++) {
        float v = ax[e];
        u16 h = bf16_of(v);
        Ah[srow][shalf + e] = h;
        Al[srow][shalf + e] = bf16_of(v - f32_of(h));
      }
      const float* bx = w + (size_t)(n0 + srow) * CIN + k0 + shalf;
      #pragma unroll
      for (int e = 0; e < 16; e++)
        Bw[srow][shalf + e] = bf16_of(bx[e]);
    }
    __syncthreads();

    s16x8 af[4], alf[4], bfr[4];
    #pragma unroll
    for (int i = 0; i < 4; i++) {
      af[i]  = *(const s16x8*)&Ah[wm*64 + i*16 + li][8*g];
      alf[i] = *(const s16x8*)&Al[wm*64 + i*16 + li][8*g];
      bfr[i] = *(const s16x8*)&Bw[wn*64 + i*16 + li][8*g];
    }
    #pragma unroll
    for (int i = 0; i < 4; i++)
      #pragma unroll
      for (int j = 0; j < 4; j++) {
        acc[i][j] = __builtin_amdgcn_mfma_f32_16x16x32_bf16(af[i],  bfr[j], acc[i][j], 0, 0, 0);
        acc[i][j] = __builtin_amdgcn_mfma_f32_16x16x32_bf16(alf[i], bfr[j], acc[i][j], 0, 0, 0);
      }
  }

  // ---- transpose epilogues ----
  __syncthreads();                       // staging LDS done
  u16 (*T)[TP] = (u16(*)[TP])smem;
  const int n    = m0 >> 10;
  const int tok0 = m0 & 1023;
  const int d0   = n0 >> 3;

  auto fillT = [&](bool lo) {
    #pragma unroll
    for (int j = 0; j < 4; j++) {
      const int cl = wn*64 + j*16 + li;
      const float bv_ = bias[n0 + cl];
      #pragma unroll
      for (int i = 0; i < 4; i++) {
        const int rbase = wm*64 + i*16 + 4*g;
        #pragma unroll
        for (int r = 0; r < 4; r++) {
          float y = acc[i][j][r] + bv_;
          u16 hi = bf16_of(y);
          T[cl][rbase + r] = lo ? bf16_of(y - f32_of(hi)) : hi;
        }
      }
    }
  };
  auto scatterK = [&](u16* __restrict__ dst) {   // -> [n][h][tok][d]
    #pragma unroll
    for (int it = 0; it < 8; it++) {
      const int chunk = tid + 256*it;
      const int h  = chunk >> 8;
      const int rem = chunk & 255;
      const int tl = rem >> 1;
      const int dc = rem & 1;
      s16x8 o;
      #pragma unroll
      for (int e = 0; e < 8; e++)
        o[e] = (short)T[(dc*8 + e)*8 + h][tl];
      *(s16x8*)&dst[(((size_t)(n*NH + h))*SEQ + tok0 + tl)*DK + d0 + dc*8] = o;
    }
  };

  if (z == 0) {
    fillT(false); __syncthreads(); scatterK(qht);
    __syncthreads();
    fillT(true);  __syncthreads(); scatterK(qlt);
  } else if (z == 1) {
    fillT(false); __syncthreads(); scatterK(kt_);
  } else {
    fillT(false); __syncthreads();
    #pragma unroll
    for (int it = 0; it < 8; it++) {           // -> [n][h][d][tok]
      const int chunk = tid + 256*it;
      const int h  = chunk >> 8;
      const int rem = chunk & 255;
      const int dl = rem >> 4;
      const int tc = rem & 15;
      s16x8 o = *(const s16x8*)&T[dl*8 + h][tc*8];
      *(s16x8*)&vt_[(((size_t)(n*NH + h))*DK + d0 + dl)*SEQ + tok0 + tc*8] = o;
    }
  }
}

#define KT 32
#define PP 36   // Pbuf row pad (f32): 2-way bank alias only

// ---------------- single-sweep attention: NO barriers in k-loop ----------------
// Stores unnormalized p (bf16) to scratch [n][h][q][k]; rinv to scratch; ctx scaled here.
__global__ __launch_bounds__(512, 4)
void attn_single(const u16* __restrict__ qht, const u16* __restrict__ qlt,
                 const u16* __restrict__ kt_, const u16* __restrict__ vt_,
                 u16* __restrict__ pg, float* __restrict__ rg,
                 float* __restrict__ ctx_out)
{
  __shared__ __align__(16) float smem[16*520];          // 33280 B (Pbuf + ctx transpose)
  float (*Pb)[16][PP] = (float(*)[16][PP])smem;         // [NH][16][36]

  const int tid  = threadIdx.x;
  const int wid  = tid >> 6, lane = tid & 63;
  const int g    = lane >> 4, li  = lane & 15;
  const int h    = wid;
  const int n    = blockIdx.x >> 6;
  const int q0   = (blockIdx.x & 63) * 16;

  const u16* Kn = kt_ + (size_t)n * NH * SEQ * DK;
  const u16* Vn = vt_ + (size_t)n * NH * DK * SEQ;
  const float SC2 = 0.18033688011112042f;   // (1/8) * log2(e)

  s16x8 qhf[2], qlf[2];
  {
    const size_t ro = ((size_t)(n*NH + h)*SEQ + q0 + li)*DK + 8*g;
    qhf[0] = *(const s16x8*)(qht + ro);
    qhf[1] = *(const s16x8*)(qht + ro + 32);
    qlf[0] = *(const s16x8*)(qlt + ro);
    qlf[1] = *(const s16x8*)(qlt + ro + 32);
  }

  auto loadK = [&](s16x8 (&kf)[2][2], int k0) {
    const u16* kp = Kn + ((size_t)h*SEQ + k0 + li)*DK + 8*g;
    kf[0][0] = *(const s16x8*)(kp);
    kf[0][1] = *(const s16x8*)(kp + 32);
    kf[1][0] = *(const s16x8*)(kp + 16*DK);
    kf[1][1] = *(const s16x8*)(kp + 16*DK + 32);
  };
  auto loadV = [&](s16x8 (&vf)[4], int k0) {
    const u16* vp = Vn + (size_t)h*DK*SEQ + k0 + 8*g;
    #pragma unroll
    for (int j = 0; j < 4; j++)
      vf[j] = *(const s16x8*)(vp + (size_t)(16*j + li)*SEQ);
  };

  float l_[4] = {0.f, 0.f, 0.f, 0.f};
  f32x4 ctx[4];
  #pragma unroll
  for (int j = 0; j < 4; j++) ctx[j] = f32x4{0.f, 0.f, 0.f, 0.f};

  u16* prow = pg + ((size_t)(n*NH + h)*SEQ + q0 + li)*SEQ + 8*g;

  auto tilec = [&](s16x8 (&kf)[2][2], s16x8 (&vf)[4], int k0) {
    f32x4 P[2];
    #pragma unroll
    for (int t = 0; t < 2; t++) {
      f32x4 a = f32x4{0.f,0.f,0.f,0.f}, c = f32x4{0.f,0.f,0.f,0.f};
      a = __builtin_amdgcn_mfma_f32_16x16x32_bf16(qhf[0], kf[t][0], a, 0, 0, 0);
      a = __builtin_amdgcn_mfma_f32_16x16x32_bf16(qhf[1], kf[t][1], a, 0, 0, 0);
      c = __builtin_amdgcn_mfma_f32_16x16x32_bf16(qlf[0], kf[t][0], c, 0, 0, 0);
      c = __builtin_amdgcn_mfma_f32_16x16x32_bf16(qlf[1], kf[t][1], c, 0, 0, 0);
      #pragma unroll
      for (int r = 0; r < 4; r++) {
        P[t][r] = __builtin_exp2f((a[r] + c[r]) * SC2);   // unnormalized
        l_[r]  += P[t][r];
      }
    }
    #pragma unroll
    for (int t = 0; t < 2; t++)
      #pragma unroll
      for (int r = 0; r < 4; r++)
        Pb[h][4*g + r][16*t + li] = P[t][r];

    // wave-private LDS RAW (no barrier): read back as k-contiguous row li
    f32x4 p0 = *(const f32x4*)&Pb[h][li][8*g];
    f32x4 p1 = *(const f32x4*)&Pb[h][li][8*g + 4];
    s16x8 pa;
    #pragma unroll
    for (int e = 0; e < 4; e++) { pa[e] = (short)bf16_of(p0[e]); pa[e+4] = (short)bf16_of(p1[e]); }

    *(s16x8*)(prow + k0) = pa;                 // p store: 16B/lane, dense rows

    #pragma unroll
    for (int j = 0; j < 4; j++)
      ctx[j] = __builtin_amdgcn_mfma_f32_16x16x32_bf16(pa, vf[j], ctx[j], 0, 0, 0);
  };

  {
    s16x8 kA[2][2], kB[2][2], vA[4], vB[4];
    loadK(kA, 0);  loadV(vA, 0);
    loadK(kB, KT); loadV(vB, KT);
    for (int k0 = 0; k0 < SEQ; k0 += 2*KT) {
      tilec(kA, vA, k0);
      loadK(kA, (k0 + 2*KT) & (SEQ-1));
      loadV(vA, (k0 + 2*KT) & (SEQ-1));
      tilec(kB, vB, k0 + KT);
      loadK(kB, (k0 + 3*KT) & (SEQ-1));
      loadV(vB, (k0 + 3*KT) & (SEQ-1));
    }
  }

  float rinv[4];
  #pragma unroll
  for (int r = 0; r < 4; r++) {
    float l = l_[r];
    #pragma unroll
    for (int off = 1; off < 16; off <<= 1)
      l += __shfl_xor(l, off, 64);
    rinv[r] = 1.0f / l;
  }
  if (li == 0) {
    #pragma unroll
    for (int r = 0; r < 4; r++)
      rg[(size_t)(n*NH + h)*SEQ + q0 + 4*g + r] = rinv[r];
  }
  #pragma unroll
  for (int j = 0; j < 4; j++)
    #pragma unroll
    for (int r = 0; r < 4; r++)
      ctx[j][r] *= rinv[r];

  // ---- context epilogue via LDS transpose ----
  __syncthreads();
  float* cs = smem;                         // [16][520]
  #pragma unroll
  for (int j = 0; j < 4; j++) {
    const int d = 16*j + li;
    #pragma unroll
    for (int r = 0; r < 4; r++)
      cs[(4*g + r)*520 + d*8 + h] = ctx[j][r];
  }
  __syncthreads();
  #pragma unroll
  for (int it = 0; it < 4; it++) {
    const int fi = tid + 512*it;
    const int r = fi >> 7, c4 = fi & 127;
    f32x4 v = *(const f32x4*)&cs[r*520 + c4*4];
    *(f32x4*)(ctx_out + (size_t)(n*SEQ + q0 + r) * CIN + c4*4) = v;
  }
}

// ---------------- streaming normalize + head-interleave transpose ----------------
__global__ __launch_bounds__(256, 8)
void norm_kernel(const u16* __restrict__ pg, const float* __restrict__ rg,
                 float* __restrict__ attn_out)
{
  __shared__ float rv[4][8];
  const int tid = threadIdx.x;
  const int b   = blockIdx.x;          // 2048
  const int n   = b >> 8;
  const int q4  = (b & 255) * 4;
  if (tid < 32)
    rv[tid >> 3][tid & 7] = rg[(size_t)(n*NH + (tid & 7))*SEQ + q4 + (tid >> 3)];
  __syncthreads();

  const int k4 = tid * 4;
  #pragma unroll
  for (int qq = 0; qq < 4; qq++) {
    const int q = q4 + qq;
    uint2 ph[8];
    #pragma unroll
    for (int hh = 0; hh < 8; hh++)
      ph[hh] = *(const uint2*)(pg + ((size_t)(n*NH + hh)*SEQ + q)*SEQ + k4);
    float* dst = attn_out + ((size_t)(n*SEQ + q)*SEQ + k4)*NH;
    #pragma unroll
    for (int kk = 0; kk < 4; kk++) {
      f32x4 lo, hi;
      #pragma unroll
      for (int hh = 0; hh < 4; hh++) {
        unsigned wl = (kk < 2) ? ph[hh].x     : ph[hh].y;
        unsigned wh = (kk < 2) ? ph[hh+4].x   : ph[hh+4].y;
        lo[hh] = f32_of((u16)(wl >> ((kk & 1)*16))) * rv[qq][hh];
        hi[hh] = f32_of((u16)(wh >> ((kk & 1)*16))) * rv[qq][hh+4];
      }
      *(f32x4*)(dst + kk*8)     = lo;
      *(f32x4*)(dst + kk*8 + 4) = hi;
    }
  }
}

// ---------------- fallback two-pass attention (R4-style, known-good) ----------------
__global__ __launch_bounds__(512, 4)
void attn_kernel(const u16* __restrict__ qht, const u16* __restrict__ qlt,
                 const u16* __restrict__ kt_, const u16* __restrict__ vt_,
                 float* __restrict__ ctx_out, float* __restrict__ attn_out)
{
  __shared__ __align__(16) float Pbuf[2][NH][16][PP];

  const int tid  = threadIdx.x;
  const int wid  = tid >> 6, lane = tid & 63;
  const int g    = lane >> 4, li  = lane & 15;
  const int h    = wid;
  const int n    = blockIdx.x >> 6;
  const int q0   = (blockIdx.x & 63) * 16;

  const u16* Kn = kt_ + (size_t)n * NH * SEQ * DK;
  const u16* Vn = vt_ + (size_t)n * NH * DK * SEQ;
  const float SC2 = 0.18033688011112042f;

  s16x8 qhf[2], qlf[2];
  {
    const size_t ro = ((size_t)(n*NH + h)*SEQ + q0 + li)*DK + 8*g;
    qhf[0] = *(const s16x8*)(qht + ro);
    qhf[1] = *(const s16x8*)(qht + ro + 32);
    qlf[0] = *(const s16x8*)(qlt + ro);
    qlf[1] = *(const s16x8*)(qlt + ro + 32);
  }

  auto loadK = [&](s16x8 (&kf)[2][2], int k0) {
    const u16* kp = Kn + ((size_t)h*SEQ + k0 + li)*DK + 8*g;
    kf[0][0] = *(const s16x8*)(kp);
    kf[0][1] = *(const s16x8*)(kp + 32);
    kf[1][0] = *(const s16x8*)(kp + 16*DK);
    kf[1][1] = *(const s16x8*)(kp + 16*DK + 32);
  };
  auto loadV = [&](s16x8 (&vf)[4], int k0) {
    const u16* vp = Vn + (size_t)h*DK*SEQ + k0 + 8*g;
    #pragma unroll
    for (int j = 0; j < 4; j++)
      vf[j] = *(const s16x8*)(vp + (size_t)(16*j + li)*SEQ);
  };

  float l_[4] = {0.f, 0.f, 0.f, 0.f};
  auto p1c = [&](s16x8 (&kf)[2][2]) {
    #pragma unroll
    for (int t = 0; t < 2; t++) {
      f32x4 a = f32x4{0.f,0.f,0.f,0.f}, c = f32x4{0.f,0.f,0.f,0.f};
      a = __builtin_amdgcn_mfma_f32_16x16x32_bf16(qhf[0], kf[t][0], a, 0, 0, 0);
      a = __builtin_amdgcn_mfma_f32_16x16x32_bf16(qhf[1], kf[t][1], a, 0, 0, 0);
      c = __builtin_amdgcn_mfma_f32_16x16x32_bf16(qlf[0], kf[t][0], c, 0, 0, 0);
      c = __builtin_amdgcn_mfma_f32_16x16x32_bf16(qlf[1], kf[t][1], c, 0, 0, 0);
      #pragma unroll
      for (int r = 0; r < 4; r++)
        l_[r] += __builtin_exp2f((a[r] + c[r]) * SC2);
    }
  };

  {
    s16x8 kA[2][2], kB[2][2];
    loadK(kA, 0);
    for (int k0 = 0; k0 < SEQ; k0 += 2*KT) {
      loadK(kB, k0 + KT);
      p1c(kA);
      loadK(kA, (k0 + 2*KT) & (SEQ-1));
      p1c(kB);
    }
  }

  float rinv[4];
  #pragma unroll
  for (int r = 0; r < 4; r++) {
    float l = l_[r];
    #pragma unroll
    for (int off = 1; off < 16; off <<= 1)
      l += __shfl_xor(l, off, 64);
    rinv[r] = 1.0f / l;
  }

  f32x4 ctx[4];
  #pragma unroll
  for (int j = 0; j < 4; j++) ctx[j] = f32x4{0.f, 0.f, 0.f, 0.f};

  auto p2c = [&](s16x8 (&kf)[2][2], s16x8 (&vf)[4], int k0) {
    const int bufi = (k0 >> 5) & 1;
    f32x4 P[2];
    #pragma unroll
    for (int t = 0; t < 2; t++) {
      f32x4 a = f32x4{0.f,0.f,0.f,0.f}, c = f32x4{0.f,0.f,0.f,0.f};
      a = __builtin_amdgcn_mfma_f32_16x16x32_bf16(qhf[0], kf[t][0], a, 0, 0, 0);
      a = __builtin_amdgcn_mfma_f32_16x16x32_bf16(qhf[1], kf[t][1], a, 0, 0, 0);
      c = __builtin_amdgcn_mfma_f32_16x16x32_bf16(qlf[0], kf[t][0], c, 0, 0, 0);
      c = __builtin_amdgcn_mfma_f32_16x16x32_bf16(qlf[1], kf[t][1], c, 0, 0, 0);
      #pragma unroll
      for (int r = 0; r < 4; r++)
        P[t][r] = __builtin_exp2f((a[r] + c[r]) * SC2) * rinv[r];
    }
    #pragma unroll
    for (int t = 0; t < 2; t++)
      #pragma unroll
      for (int r = 0; r < 4; r++)
        Pbuf[bufi][h][4*g + r][16*t + li] = P[t][r];

    f32x4 p0 = *(const f32x4*)&Pbuf[bufi][h][li][8*g];
    f32x4 p1 = *(const f32x4*)&Pbuf[bufi][h][li][8*g + 4];
    s16x8 pa;
    #pragma unroll
    for (int e = 0; e < 4; e++) { pa[e] = (short)bf16_of(p0[e]); pa[e+4] = (short)bf16_of(p1[e]); }
    #pragma unroll
    for (int j = 0; j < 4; j++)
      ctx[j] = __builtin_amdgcn_mfma_f32_16x16x32_bf16(pa, vf[j], ctx[j], 0, 0, 0);

    __syncthreads();
    {
      const int c  = tid & 31;
      const int r  = (tid >> 5) & 15;
      float4 o0, o1;
      o0.x = Pbuf[bufi][0][r][c]; o0.y = Pbuf[bufi][1][r][c];
      o0.z = Pbuf[bufi][2][r][c]; o0.w = Pbuf[bufi][3][r][c];
      o1.x = Pbuf[bufi][4][r][c]; o1.y = Pbuf[bufi][5][r][c];
      o1.z = Pbuf[bufi][6][r][c]; o1.w = Pbuf[bufi][7][r][c];
      float4* dst = (float4*)(attn_out + ((size_t)(n*SEQ + q0 + r) * SEQ + (k0 + c)) * NH);
      dst[0] = o0; dst[1] = o1;
    }
  };

  {
    s16x8 kA[2][2], kB[2][2], vA[4], vB[4];
    loadK(kA, 0); loadK(kB, KT);
    loadV(vA, 0);
    for (int k0 = 0; k0 < SEQ; k0 += 2*KT) {
      loadV(vB, k0 + KT);
      p2c(kA, vA, k0);
      loadK(kA, (k0 + 2*KT) & (SEQ-1));
      loadV(vA, (k0 + 2*KT) & (SEQ-1));
      p2c(kB, vB, k0 + KT);
      loadK(kB, (k0 + 3*KT) & (SEQ-1));
    }
  }

  __syncthreads();
  float* cs = (float*)Pbuf;
  #pragma unroll
  for (int j = 0; j < 4; j++) {
    const int d = 16*j + li;
    #pragma unroll
    for (int r = 0; r < 4; r++)
      cs[(4*g + r)*520 + d*8 + h] = ctx[j][r];
  }
  __syncthreads();
  #pragma unroll
  for (int it = 0; it < 4; it++) {
    const int fi = tid + 512*it;
    const int r = fi >> 7, c4 = fi & 127;
    f32x4 v = *(const f32x4*)&cs[r*520 + c4*4];
    *(f32x4*)(ctx_out + (size_t)(n*SEQ + q0 + r) * CIN + c4*4) = v;
  }
}

// ---------------- launch ----------------
extern "C" void kernel_launch(void* const* d_in, const int* in_sizes, int n_in,
                              void* d_out, int out_size, void* d_ws, size_t ws_size,
                              hipStream_t stream) {
  const float* x  = (const float*)d_in[0];
  const float* wq = (const float*)d_in[1];
  const float* bq = (const float*)d_in[2];
  const float* wk = (const float*)d_in[3];
  const float* bk = (const float*)d_in[4];
  const float* wv = (const float*)d_in[5];
  const float* bv = (const float*)d_in[6];

  float* ctx_out  = (float*)d_out;
  float* attn_out = ctx_out + (size_t)NB * SEQ * CIN;

  u16* qht = (u16*)d_ws;
  u16* qlt = qht + (size_t)MROWS * CIN;
  u16* kt  = qlt + (size_t)MROWS * CIN;
  u16* vt  = kt  + (size_t)MROWS * CIN;

  const size_t qkv_bytes = 4 * (size_t)MROWS * CIN * 2;                 // 32 MB
  const size_t p_bytes   = (size_t)NB * NH * SEQ * SEQ * 2;             // 128 MB
  const size_t r_bytes   = (size_t)NB * NH * SEQ * 4;                   // 256 KB

  dim3 pg_(MROWS / BM, CIN / BN, 3);
  proj_kernel<<<pg_, 256, 0, stream>>>(x, wq, bq, wk, bk, wv, bv, qht, qlt, kt, vt);

  if (ws_size >= qkv_bytes + p_bytes + r_bytes) {
    u16*   pgm = (u16*)((char*)d_ws + qkv_bytes);
    float* rg  = (float*)((char*)d_ws + qkv_bytes + p_bytes);
    attn_single<<<dim3(NB * SEQ / 16), 512, 0, stream>>>(qht, qlt, kt, vt, pgm, rg, ctx_out);
    norm_kernel<<<dim3(NB * SEQ / 4), 256, 0, stream>>>(pgm, rg, attn_out);
  } else {
    attn_kernel<<<dim3(NB * SEQ / 16), 512, 0, stream>>>(qht, qlt, kt, vt, ctx_out, attn_out);
  }
}

// Round 7
// 320.103 us; speedup vs baseline: 1.0053x; 1.0053x over previous
//
#include <hip/hip_runtime.h>

typedef float f32x4 __attribute__((ext_vector_type(4)));
typedef short s16x8 __attribute__((ext_vector_type(8)));
typedef unsigned short u16;

#define NB 8
#define SEQ 1024
#define CIN 512
#define NH 8
#define DK 64
#define MROWS (NB*SEQ)

__device__ __forceinline__ u16 bf16_of(float f) {
  unsigned u = __builtin_bit_cast(unsigned, f);
  u += 0x7fffu + ((u >> 16) & 1u);           // RTNE
  return (u16)(u >> 16);
}
__device__ __forceinline__ float f32_of(u16 b) {
  unsigned u = ((unsigned)b) << 16;
  return __builtin_bit_cast(float, u);
}

// ---------------- QKV projection: Y = X W^T + b  (bf16 MFMA, X split hi/lo) ----------------
// All outputs transposed to head-major: q/k -> [n][h][tok][d], v -> [n][h][d][tok]
#define BM 128
#define BN 128
#define BK 32
#define LDP 40    // staging row pad (u16)
#define TP  136   // transpose buffer row pad (u16)

__global__ __launch_bounds__(256, 2)
void proj_kernel(const float* __restrict__ x,
                 const float* __restrict__ wq, const float* __restrict__ bq,
                 const float* __restrict__ wk, const float* __restrict__ bk,
                 const float* __restrict__ wv, const float* __restrict__ bv,
                 u16* __restrict__ qht, u16* __restrict__ qlt,
                 u16* __restrict__ kt_, u16* __restrict__ vt_)
{
  __shared__ __align__(16) u16 smem[128 * TP];
  u16 (*Ah)[LDP] = (u16(*)[LDP])(smem);
  u16 (*Al)[LDP] = (u16(*)[LDP])(smem + 128*LDP);
  u16 (*Bw)[LDP] = (u16(*)[LDP])(smem + 256*LDP);

  const int tid  = threadIdx.x;
  const int wid  = tid >> 6, lane = tid & 63;
  const int g    = lane >> 4, li  = lane & 15;
  const int m0   = blockIdx.x * BM;
  const int n0   = blockIdx.y * BN;
  const int z    = blockIdx.z;

  const float* w    = (z == 0) ? wq : (z == 1) ? wk : wv;
  const float* bias = (z == 0) ? bq : (z == 1) ? bk : bv;

  const int wm = wid >> 1, wn = wid & 1;

  f32x4 acc[4][4];
  #pragma unroll
  for (int i = 0; i < 4; i++)
    #pragma unroll
    for (int j = 0; j < 4; j++)
      acc[i][j] = f32x4{0.f, 0.f, 0.f, 0.f};

  const int srow  = tid >> 1;
  const int shalf = (tid & 1) * 16;

  for (int k0 = 0; k0 < CIN; k0 += BK) {
    __syncthreads();
    {
      const float* ax = x + (size_t)(m0 + srow) * CIN + k0 + shalf;
      #pragma unroll
      for (int e = 0; e < 16; e++) {
        float v = ax[e];
        u16 h = bf16_of(v);
        Ah[srow][shalf + e] = h;
        Al[srow][shalf + e] = bf16_of(v - f32_of(h));
      }
      const float* bx = w + (size_t)(n0 + srow) * CIN + k0 + shalf;
      #pragma unroll
      for (int e = 0; e < 16; e++)
        Bw[srow][shalf + e] = bf16_of(bx[e]);
    }
    __syncthreads();

    s16x8 af[4], alf[4], bfr[4];
    #pragma unroll
    for (int i = 0; i < 4; i++) {
      af[i]  = *(const s16x8*)&Ah[wm*64 + i*16 + li][8*g];
      alf[i] = *(const s16x8*)&Al[wm*64 + i*16 + li][8*g];
      bfr[i] = *(const s16x8*)&Bw[wn*64 + i*16 + li][8*g];
    }
    #pragma unroll
    for (int i = 0; i < 4; i++)
      #pragma unroll
      for (int j = 0; j < 4; j++) {
        acc[i][j] = __builtin_amdgcn_mfma_f32_16x16x32_bf16(af[i],  bfr[j], acc[i][j], 0, 0, 0);
        acc[i][j] = __builtin_amdgcn_mfma_f32_16x16x32_bf16(alf[i], bfr[j], acc[i][j], 0, 0, 0);
      }
  }

  // ---- transpose epilogues ----
  __syncthreads();                       // staging LDS done
  u16 (*T)[TP] = (u16(*)[TP])smem;
  const int n    = m0 >> 10;
  const int tok0 = m0 & 1023;
  const int d0   = n0 >> 3;

  auto fillT = [&](bool lo) {
    #pragma unroll
    for (int j = 0; j < 4; j++) {
      const int cl = wn*64 + j*16 + li;
      const float bv_ = bias[n0 + cl];
      #pragma unroll
      for (int i = 0; i < 4; i++) {
        const int rbase = wm*64 + i*16 + 4*g;
        #pragma unroll
        for (int r = 0; r < 4; r++) {
          float y = acc[i][j][r] + bv_;
          u16 hi = bf16_of(y);
          T[cl][rbase + r] = lo ? bf16_of(y - f32_of(hi)) : hi;
        }
      }
    }
  };
  auto scatterK = [&](u16* __restrict__ dst) {   // -> [n][h][tok][d]
    #pragma unroll
    for (int it = 0; it < 8; it++) {
      const int chunk = tid + 256*it;
      const int h  = chunk >> 8;
      const int rem = chunk & 255;
      const int tl = rem >> 1;
      const int dc = rem & 1;
      s16x8 o;
      #pragma unroll
      for (int e = 0; e < 8; e++)
        o[e] = (short)T[(dc*8 + e)*8 + h][tl];
      *(s16x8*)&dst[(((size_t)(n*NH + h))*SEQ + tok0 + tl)*DK + d0 + dc*8] = o;
    }
  };

  if (z == 0) {
    fillT(false); __syncthreads(); scatterK(qht);
    __syncthreads();
    fillT(true);  __syncthreads(); scatterK(qlt);
  } else if (z == 1) {
    fillT(false); __syncthreads(); scatterK(kt_);
  } else {
    fillT(false); __syncthreads();
    #pragma unroll
    for (int it = 0; it < 8; it++) {           // -> [n][h][d][tok]
      const int chunk = tid + 256*it;
      const int h  = chunk >> 8;
      const int rem = chunk & 255;
      const int dl = rem >> 4;
      const int tc = rem & 15;
      s16x8 o = *(const s16x8*)&T[dl*8 + h][tc*8];
      *(s16x8*)&vt_[(((size_t)(n*NH + h))*DK + d0 + dl)*SEQ + tok0 + tc*8] = o;
    }
  }
}

#define KT 32
#define PP 36   // Pbuf row pad (f32): 2-way bank alias only

// ---------------- single-sweep attention: NO barriers in k-loop ----------------
// p (bf16, unnormalized) -> scratch tiles [n][h][qt(64)][k(1024)][qi(16)]
// (each 16q x 32k wave-tile = 1024 B contiguous; lane L stores 16 B at base+L*16)
__global__ __launch_bounds__(512, 4)
void attn_single(const u16* __restrict__ qht, const u16* __restrict__ qlt,
                 const u16* __restrict__ kt_, const u16* __restrict__ vt_,
                 u16* __restrict__ pg, float* __restrict__ rg,
                 float* __restrict__ ctx_out)
{
  __shared__ __align__(16) float smem[16*520];          // 33280 B (Pbuf + ctx transpose)
  float (*Pb)[16][PP] = (float(*)[16][PP])smem;         // [NH][16][36]

  const int tid  = threadIdx.x;
  const int wid  = tid >> 6, lane = tid & 63;
  const int g    = lane >> 4, li  = lane & 15;
  const int h    = wid;
  const int n    = blockIdx.x >> 6;
  const int q0   = (blockIdx.x & 63) * 16;

  const u16* Kn = kt_ + (size_t)n * NH * SEQ * DK;
  const u16* Vn = vt_ + (size_t)n * NH * DK * SEQ;
  const float SC2 = 0.18033688011112042f;   // (1/8) * log2(e)

  s16x8 qhf[2], qlf[2];
  {
    const size_t ro = ((size_t)(n*NH + h)*SEQ + q0 + li)*DK + 8*g;
    qhf[0] = *(const s16x8*)(qht + ro);
    qhf[1] = *(const s16x8*)(qht + ro + 32);
    qlf[0] = *(const s16x8*)(qlt + ro);
    qlf[1] = *(const s16x8*)(qlt + ro + 32);
  }

  auto loadK = [&](s16x8 (&kf)[2][2], int k0) {
    const u16* kp = Kn + ((size_t)h*SEQ + k0 + li)*DK + 8*g;
    kf[0][0] = *(const s16x8*)(kp);
    kf[0][1] = *(const s16x8*)(kp + 32);
    kf[1][0] = *(const s16x8*)(kp + 16*DK);
    kf[1][1] = *(const s16x8*)(kp + 16*DK + 32);
  };
  auto loadV = [&](s16x8 (&vf)[4], int k0) {
    const u16* vp = Vn + (size_t)h*DK*SEQ + k0 + 8*g;
    #pragma unroll
    for (int j = 0; j < 4; j++)
      vf[j] = *(const s16x8*)(vp + (size_t)(16*j + li)*SEQ);
  };

  float l_[4] = {0.f, 0.f, 0.f, 0.f};
  f32x4 ctx[4];
  #pragma unroll
  for (int j = 0; j < 4; j++) ctx[j] = f32x4{0.f, 0.f, 0.f, 0.f};

  // tile-linear p base for this (n,h,q-tile)
  u16* pb = pg + (((size_t)(n*NH + h)*64 + (q0 >> 4)) * 1024) * 16;
  const int kl = lane >> 1;            // k_local 0..31
  const int qb = (lane & 1) * 8;       // qi base 0/8

  auto tilec = [&](s16x8 (&kf)[2][2], s16x8 (&vf)[4], int k0) {
    f32x4 P[2];
    #pragma unroll
    for (int t = 0; t < 2; t++) {
      f32x4 a = f32x4{0.f,0.f,0.f,0.f}, c = f32x4{0.f,0.f,0.f,0.f};
      a = __builtin_amdgcn_mfma_f32_16x16x32_bf16(qhf[0], kf[t][0], a, 0, 0, 0);
      a = __builtin_amdgcn_mfma_f32_16x16x32_bf16(qhf[1], kf[t][1], a, 0, 0, 0);
      c = __builtin_amdgcn_mfma_f32_16x16x32_bf16(qlf[0], kf[t][0], c, 0, 0, 0);
      c = __builtin_amdgcn_mfma_f32_16x16x32_bf16(qlf[1], kf[t][1], c, 0, 0, 0);
      #pragma unroll
      for (int r = 0; r < 4; r++) {
        P[t][r] = __builtin_exp2f((a[r] + c[r]) * SC2);   // unnormalized
        l_[r]  += P[t][r];
      }
    }
    #pragma unroll
    for (int t = 0; t < 2; t++)
      #pragma unroll
      for (int r = 0; r < 4; r++)
        Pb[h][4*g + r][16*t + li] = P[t][r];

    // wave-private LDS RAW (no barrier):
    // (1) PV A-fragment: q=li, k=8g..8g+7
    f32x4 p0 = *(const f32x4*)&Pb[h][li][8*g];
    f32x4 p1 = *(const f32x4*)&Pb[h][li][8*g + 4];
    s16x8 pa;
    #pragma unroll
    for (int e = 0; e < 4; e++) { pa[e] = (short)bf16_of(p0[e]); pa[e+4] = (short)bf16_of(p1[e]); }
    #pragma unroll
    for (int j = 0; j < 4; j++)
      ctx[j] = __builtin_amdgcn_mfma_f32_16x16x32_bf16(pa, vf[j], ctx[j], 0, 0, 0);

    // (2) tile-linear p store: lane L covers [k=kl][qi=qb..qb+7] -> 16B at base+L*16
    s16x8 ps;
    #pragma unroll
    for (int e = 0; e < 8; e++)
      ps[e] = (short)bf16_of(Pb[h][qb + e][kl]);
    *(s16x8*)(pb + (size_t)(k0 + kl)*16 + qb) = ps;
  };

  {
    s16x8 kA[2][2], kB[2][2], vA[4], vB[4];
    loadK(kA, 0);  loadV(vA, 0);
    loadK(kB, KT); loadV(vB, KT);
    for (int k0 = 0; k0 < SEQ; k0 += 2*KT) {
      tilec(kA, vA, k0);
      loadK(kA, (k0 + 2*KT) & (SEQ-1));
      loadV(vA, (k0 + 2*KT) & (SEQ-1));
      tilec(kB, vB, k0 + KT);
      loadK(kB, (k0 + 3*KT) & (SEQ-1));
      loadV(vB, (k0 + 3*KT) & (SEQ-1));
    }
  }

  float rinv[4];
  #pragma unroll
  for (int r = 0; r < 4; r++) {
    float l = l_[r];
    #pragma unroll
    for (int off = 1; off < 16; off <<= 1)
      l += __shfl_xor(l, off, 64);
    rinv[r] = 1.0f / l;
  }
  if (li == 0) {
    #pragma unroll
    for (int r = 0; r < 4; r++)
      rg[(size_t)(n*NH + h)*SEQ + q0 + 4*g + r] = rinv[r];
  }
  #pragma unroll
  for (int j = 0; j < 4; j++)
    #pragma unroll
    for (int r = 0; r < 4; r++)
      ctx[j][r] *= rinv[r];

  // ---- context epilogue via LDS transpose ----
  __syncthreads();
  float* cs = smem;                         // [16][520]
  #pragma unroll
  for (int j = 0; j < 4; j++) {
    const int d = 16*j + li;
    #pragma unroll
    for (int r = 0; r < 4; r++)
      cs[(4*g + r)*520 + d*8 + h] = ctx[j][r];
  }
  __syncthreads();
  #pragma unroll
  for (int it = 0; it < 4; it++) {
    const int fi = tid + 512*it;
    const int r = fi >> 7, c4 = fi & 127;
    f32x4 v = *(const f32x4*)&cs[r*520 + c4*4];
    *(f32x4*)(ctx_out + (size_t)(n*SEQ + q0 + r) * CIN + c4*4) = v;
  }
}

// ---------------- streaming normalize: p tiles -> attn [q][k][h] ----------------
// block = (n, q-tile of 16). All streams dense 32B/lane.
__global__ __launch_bounds__(256, 4)
void norm_kernel(const u16* __restrict__ pg, const float* __restrict__ rg,
                 float* __restrict__ attn_out)
{
  __shared__ float rv[NH][16];
  const int tid = threadIdx.x;
  const int b   = blockIdx.x;          // NB*64
  const int n   = b >> 6;
  const int qt  = b & 63;
  const int q0  = qt * 16;

  if (tid < 128)
    rv[tid >> 4][tid & 15] = rg[(size_t)(n*NH + (tid >> 4))*SEQ + q0 + (tid & 15)];
  __syncthreads();

  for (int it = 0; it < 4; ++it) {
    const int k = it*256 + tid;
    s16x8 c[NH][2];
    #pragma unroll
    for (int hh = 0; hh < NH; hh++) {
      const u16* src = pg + (((size_t)(n*NH + hh)*64 + qt)*1024 + k)*16;
      c[hh][0] = *(const s16x8*)(src);
      c[hh][1] = *(const s16x8*)(src + 8);
    }
    float* dst = attn_out + ((size_t)(n*SEQ + q0)*SEQ + k)*NH;
    #pragma unroll
    for (int qi = 0; qi < 16; qi++) {
      f32x4 lo, hi;
      #pragma unroll
      for (int hh = 0; hh < 4; hh++) {
        lo[hh] = f32_of((u16)c[hh][qi >> 3][qi & 7])   * rv[hh][qi];
        hi[hh] = f32_of((u16)c[hh+4][qi >> 3][qi & 7]) * rv[hh+4][qi];
      }
      *(f32x4*)(dst + (size_t)qi*SEQ*NH)     = lo;
      *(f32x4*)(dst + (size_t)qi*SEQ*NH + 4) = hi;
    }
  }
}

// ---------------- fallback two-pass attention (R4-style, known-good) ----------------
__global__ __launch_bounds__(512, 4)
void attn_kernel(const u16* __restrict__ qht, const u16* __restrict__ qlt,
                 const u16* __restrict__ kt_, const u16* __restrict__ vt_,
                 float* __restrict__ ctx_out, float* __restrict__ attn_out)
{
  __shared__ __align__(16) float Pbuf[2][NH][16][PP];

  const int tid  = threadIdx.x;
  const int wid  = tid >> 6, lane = tid & 63;
  const int g    = lane >> 4, li  = lane & 15;
  const int h    = wid;
  const int n    = blockIdx.x >> 6;
  const int q0   = (blockIdx.x & 63) * 16;

  const u16* Kn = kt_ + (size_t)n * NH * SEQ * DK;
  const u16* Vn = vt_ + (size_t)n * NH * DK * SEQ;
  const float SC2 = 0.18033688011112042f;

  s16x8 qhf[2], qlf[2];
  {
    const size_t ro = ((size_t)(n*NH + h)*SEQ + q0 + li)*DK + 8*g;
    qhf[0] = *(const s16x8*)(qht + ro);
    qhf[1] = *(const s16x8*)(qht + ro + 32);
    qlf[0] = *(const s16x8*)(qlt + ro);
    qlf[1] = *(const s16x8*)(qlt + ro + 32);
  }

  auto loadK = [&](s16x8 (&kf)[2][2], int k0) {
    const u16* kp = Kn + ((size_t)h*SEQ + k0 + li)*DK + 8*g;
    kf[0][0] = *(const s16x8*)(kp);
    kf[0][1] = *(const s16x8*)(kp + 32);
    kf[1][0] = *(const s16x8*)(kp + 16*DK);
    kf[1][1] = *(const s16x8*)(kp + 16*DK + 32);
  };
  auto loadV = [&](s16x8 (&vf)[4], int k0) {
    const u16* vp = Vn + (size_t)h*DK*SEQ + k0 + 8*g;
    #pragma unroll
    for (int j = 0; j < 4; j++)
      vf[j] = *(const s16x8*)(vp + (size_t)(16*j + li)*SEQ);
  };

  float l_[4] = {0.f, 0.f, 0.f, 0.f};
  auto p1c = [&](s16x8 (&kf)[2][2]) {
    #pragma unroll
    for (int t = 0; t < 2; t++) {
      f32x4 a = f32x4{0.f,0.f,0.f,0.f}, c = f32x4{0.f,0.f,0.f,0.f};
      a = __builtin_amdgcn_mfma_f32_16x16x32_bf16(qhf[0], kf[t][0], a, 0, 0, 0);
      a = __builtin_amdgcn_mfma_f32_16x16x32_bf16(qhf[1], kf[t][1], a, 0, 0, 0);
      c = __builtin_amdgcn_mfma_f32_16x16x32_bf16(qlf[0], kf[t][0], c, 0, 0, 0);
      c = __builtin_amdgcn_mfma_f32_16x16x32_bf16(qlf[1], kf[t][1], c, 0, 0, 0);
      #pragma unroll
      for (int r = 0; r < 4; r++)
        l_[r] += __builtin_exp2f((a[r] + c[r]) * SC2);
    }
  };

  {
    s16x8 kA[2][2], kB[2][2];
    loadK(kA, 0);
    for (int k0 = 0; k0 < SEQ; k0 += 2*KT) {
      loadK(kB, k0 + KT);
      p1c(kA);
      loadK(kA, (k0 + 2*KT) & (SEQ-1));
      p1c(kB);
    }
  }

  float rinv[4];
  #pragma unroll
  for (int r = 0; r < 4; r++) {
    float l = l_[r];
    #pragma unroll
    for (int off = 1; off < 16; off <<= 1)
      l += __shfl_xor(l, off, 64);
    rinv[r] = 1.0f / l;
  }

  f32x4 ctx[4];
  #pragma unroll
  for (int j = 0; j < 4; j++) ctx[j] = f32x4{0.f, 0.f, 0.f, 0.f};

  auto p2c = [&](s16x8 (&kf)[2][2], s16x8 (&vf)[4], int k0) {
    const int bufi = (k0 >> 5) & 1;
    f32x4 P[2];
    #pragma unroll
    for (int t = 0; t < 2; t++) {
      f32x4 a = f32x4{0.f,0.f,0.f,0.f}, c = f32x4{0.f,0.f,0.f,0.f};
      a = __builtin_amdgcn_mfma_f32_16x16x32_bf16(qhf[0], kf[t][0], a, 0, 0, 0);
      a = __builtin_amdgcn_mfma_f32_16x16x32_bf16(qhf[1], kf[t][1], a, 0, 0, 0);
      c = __builtin_amdgcn_mfma_f32_16x16x32_bf16(qlf[0], kf[t][0], c, 0, 0, 0);
      c = __builtin_amdgcn_mfma_f32_16x16x32_bf16(qlf[1], kf[t][1], c, 0, 0, 0);
      #pragma unroll
      for (int r = 0; r < 4; r++)
        P[t][r] = __builtin_exp2f((a[r] + c[r]) * SC2) * rinv[r];
    }
    #pragma unroll
    for (int t = 0; t < 2; t++)
      #pragma unroll
      for (int r = 0; r < 4; r++)
        Pbuf[bufi][h][4*g + r][16*t + li] = P[t][r];

    f32x4 p0 = *(const f32x4*)&Pbuf[bufi][h][li][8*g];
    f32x4 p1 = *(const f32x4*)&Pbuf[bufi][h][li][8*g + 4];
    s16x8 pa;
    #pragma unroll
    for (int e = 0; e < 4; e++) { pa[e] = (short)bf16_of(p0[e]); pa[e+4] = (short)bf16_of(p1[e]); }
    #pragma unroll
    for (int j = 0; j < 4; j++)
      ctx[j] = __builtin_amdgcn_mfma_f32_16x16x32_bf16(pa, vf[j], ctx[j], 0, 0, 0);

    __syncthreads();
    {
      const int c  = tid & 31;
      const int r  = (tid >> 5) & 15;
      float4 o0, o1;
      o0.x = Pbuf[bufi][0][r][c]; o0.y = Pbuf[bufi][1][r][c];
      o0.z = Pbuf[bufi][2][r][c]; o0.w = Pbuf[bufi][3][r][c];
      o1.x = Pbuf[bufi][4][r][c]; o1.y = Pbuf[bufi][5][r][c];
      o1.z = Pbuf[bufi][6][r][c]; o1.w = Pbuf[bufi][7][r][c];
      float4* dst = (float4*)(attn_out + ((size_t)(n*SEQ + q0 + r) * SEQ + (k0 + c)) * NH);
      dst[0] = o0; dst[1] = o1;
    }
  };

  {
    s16x8 kA[2][2], kB[2][2], vA[4], vB[4];
    loadK(kA, 0); loadK(kB, KT);
    loadV(vA, 0);
    for (int k0 = 0; k0 < SEQ; k0 += 2*KT) {
      loadV(vB, k0 + KT);
      p2c(kA, vA, k0);
      loadK(kA, (k0 + 2*KT) & (SEQ-1));
      loadV(vA, (k0 + 2*KT) & (SEQ-1));
      p2c(kB, vB, k0 + KT);
      loadK(kB, (k0 + 3*KT) & (SEQ-1));
    }
  }

  __syncthreads();
  float* cs = (float*)Pbuf;
  #pragma unroll
  for (int j = 0; j < 4; j++) {
    const int d = 16*j + li;
    #pragma unroll
    for (int r = 0; r < 4; r++)
      cs[(4*g + r)*520 + d*8 + h] = ctx[j][r];
  }
  __syncthreads();
  #pragma unroll
  for (int it = 0; it < 4; it++) {
    const int fi = tid + 512*it;
    const int r = fi >> 7, c4 = fi & 127;
    f32x4 v = *(const f32x4*)&cs[r*520 + c4*4];
    *(f32x4*)(ctx_out + (size_t)(n*SEQ + q0 + r) * CIN + c4*4) = v;
  }
}

// ---------------- launch ----------------
extern "C" void kernel_launch(void* const* d_in, const int* in_sizes, int n_in,
                              void* d_out, int out_size, void* d_ws, size_t ws_size,
                              hipStream_t stream) {
  const float* x  = (const float*)d_in[0];
  const float* wq = (const float*)d_in[1];
  const float* bq = (const float*)d_in[2];
  const float* wk = (const float*)d_in[3];
  const float* bk = (const float*)d_in[4];
  const float* wv = (const float*)d_in[5];
  const float* bv = (const float*)d_in[6];

  float* ctx_out  = (float*)d_out;
  float* attn_out = ctx_out + (size_t)NB * SEQ * CIN;

  u16* qht = (u16*)d_ws;
  u16* qlt = qht + (size_t)MROWS * CIN;
  u16* kt  = qlt + (size_t)MROWS * CIN;
  u16* vt  = kt  + (size_t)MROWS * CIN;

  const size_t qkv_bytes = 4 * (size_t)MROWS * CIN * 2;                 // 32 MB
  const size_t p_bytes   = (size_t)NB * NH * SEQ * SEQ * 2;             // 128 MB
  const size_t r_bytes   = (size_t)NB * NH * SEQ * 4;                   // 256 KB

  dim3 pg_(MROWS / BM, CIN / BN, 3);
  proj_kernel<<<pg_, 256, 0, stream>>>(x, wq, bq, wk, bk, wv, bv, qht, qlt, kt, vt);

  if (ws_size >= qkv_bytes + p_bytes + r_bytes) {
    u16*   pgm = (u16*)((char*)d_ws + qkv_bytes);
    float* rg  = (float*)((char*)d_ws + qkv_bytes + p_bytes);
    attn_single<<<dim3(NB * SEQ / 16), 512, 0, stream>>>(qht, qlt, kt, vt, pgm, rg, ctx_out);
    norm_kernel<<<dim3(NB * 64), 256, 0, stream>>>(pgm, rg, attn_out);
  } else {
    attn_kernel<<<dim3(NB * SEQ / 16), 512, 0, stream>>>(qht, qlt, kt, vt, ctx_out, attn_out);
  }
}

// Round 8
// 247.454 us; speedup vs baseline: 1.3004x; 1.2936x over previous
//
#include <hip/hip_runtime.h>

typedef float f32x4 __attribute__((ext_vector_type(4)));
typedef short s16x8 __attribute__((ext_vector_type(8)));
typedef unsigned short u16;

#define NB 8
#define SEQ 1024
#define CIN 512
#define NH 8
#define DK 64
#define MROWS (NB*SEQ)

__device__ __forceinline__ u16 bf16_of(float f) {
  unsigned u = __builtin_bit_cast(unsigned, f);
  u += 0x7fffu + ((u >> 16) & 1u);           // RTNE
  return (u16)(u >> 16);
}
__device__ __forceinline__ float f32_of(u16 b) {
  unsigned u = ((unsigned)b) << 16;
  return __builtin_bit_cast(float, u);
}

// ================= layouts (all fragment-linear, u16) =================
// QF/KF: [n][h][t16(64)][ks(2)][lane(64)*8]   -- elem(L,e): tok=16t+ (L&15), d=32ks+8(L>>4)+e
// VF:    [n][h][s32(32)][j(4)][lane(64)*8]    -- elem(L,e): d=16j+(L&15), tok=32s+8(L>>4)+e
// pg:    [n][h][qt(64)][k(1024)][qi(16)]  bf16 unnormalized
// rg:    [n][h][q] f32 rinv
// cs:    [n][h][qt(64)][qi(16)][d(64)] f32 ctx (pre-scaled)

// ---------------- QKV projection (bf16 MFMA, X split hi/lo) ----------------
#define BM 128
#define BN 128
#define BK 32
#define LDP 40
#define TP  136

__global__ __launch_bounds__(256, 2)
void proj_kernel(const float* __restrict__ x,
                 const float* __restrict__ wq, const float* __restrict__ bq,
                 const float* __restrict__ wk, const float* __restrict__ bk,
                 const float* __restrict__ wv, const float* __restrict__ bv,
                 u16* __restrict__ qht, u16* __restrict__ qlt,
                 u16* __restrict__ kf_, u16* __restrict__ vf_)
{
  __shared__ __align__(16) u16 smem[128 * TP];
  u16 (*Ah)[LDP] = (u16(*)[LDP])(smem);
  u16 (*Al)[LDP] = (u16(*)[LDP])(smem + 128*LDP);
  u16 (*Bw)[LDP] = (u16(*)[LDP])(smem + 256*LDP);

  const int tid  = threadIdx.x;
  const int wid  = tid >> 6, lane = tid & 63;
  const int g    = lane >> 4, li  = lane & 15;
  const int m0   = blockIdx.x * BM;
  const int n0   = blockIdx.y * BN;
  const int z    = blockIdx.z;

  const float* w    = (z == 0) ? wq : (z == 1) ? wk : wv;
  const float* bias = (z == 0) ? bq : (z == 1) ? bk : bv;

  const int wm = wid >> 1, wn = wid & 1;

  f32x4 acc[4][4];
  #pragma unroll
  for (int i = 0; i < 4; i++)
    #pragma unroll
    for (int j = 0; j < 4; j++)
      acc[i][j] = f32x4{0.f, 0.f, 0.f, 0.f};

  const int srow  = tid >> 1;
  const int shalf = (tid & 1) * 16;

  for (int k0 = 0; k0 < CIN; k0 += BK) {
    __syncthreads();
    {
      const float* ax = x + (size_t)(m0 + srow) * CIN + k0 + shalf;
      #pragma unroll
      for (int e = 0; e < 16; e++) {
        float v = ax[e];
        u16 h = bf16_of(v);
        Ah[srow][shalf + e] = h;
        Al[srow][shalf + e] = bf16_of(v - f32_of(h));
      }
      const float* bx = w + (size_t)(n0 + srow) * CIN + k0 + shalf;
      #pragma unroll
      for (int e = 0; e < 16; e++)
        Bw[srow][shalf + e] = bf16_of(bx[e]);
    }
    __syncthreads();

    s16x8 af[4], alf[4], bfr[4];
    #pragma unroll
    for (int i = 0; i < 4; i++) {
      af[i]  = *(const s16x8*)&Ah[wm*64 + i*16 + li][8*g];
      alf[i] = *(const s16x8*)&Al[wm*64 + i*16 + li][8*g];
      bfr[i] = *(const s16x8*)&Bw[wn*64 + i*16 + li][8*g];
    }
    #pragma unroll
    for (int i = 0; i < 4; i++)
      #pragma unroll
      for (int j = 0; j < 4; j++) {
        acc[i][j] = __builtin_amdgcn_mfma_f32_16x16x32_bf16(af[i],  bfr[j], acc[i][j], 0, 0, 0);
        acc[i][j] = __builtin_amdgcn_mfma_f32_16x16x32_bf16(alf[i], bfr[j], acc[i][j], 0, 0, 0);
      }
  }

  // ---- epilogues: T[c_local][r_local] then fragment-linear scatter ----
  __syncthreads();
  u16 (*T)[TP] = (u16(*)[TP])smem;
  const int n    = m0 >> 10;
  const int tok0 = m0 & 1023;
  const int d0   = n0 >> 3;          // 16 d's per block; multiple of 16

  auto fillT = [&](bool lo) {
    #pragma unroll
    for (int j = 0; j < 4; j++) {
      const int cl = wn*64 + j*16 + li;
      const float bv_ = bias[n0 + cl];
      #pragma unroll
      for (int i = 0; i < 4; i++) {
        const int rbase = wm*64 + i*16 + 4*g;
        #pragma unroll
        for (int r = 0; r < 4; r++) {
          float y = acc[i][j][r] + bv_;
          u16 hi = bf16_of(y);
          T[cl][rbase + r] = lo ? bf16_of(y - f32_of(hi)) : hi;
        }
      }
    }
  };

  // K/Q fragment scatter: dest (t,ks,L) ; this block covers ks=d0>>5, g in {g0,g0+1}
  auto scatterF = [&](u16* __restrict__ dst) {
    const int ks = d0 >> 5;
    const int g0 = (d0 & 31) >> 3;
    #pragma unroll
    for (int it = 0; it < 8; it++) {
      const int chunk = tid + 256*it;       // 0..2047
      const int h   = chunk >> 8;
      const int rem = chunk & 255;
      const int tl  = rem >> 5;             // 0..7 local 16-tok group
      const int Lo  = rem & 31;
      const int L   = 16*g0 + Lo;
      const int dg  = Lo >> 4;              // g - g0
      const int lli = L & 15;
      s16x8 o;
      #pragma unroll
      for (int e = 0; e < 8; e++)
        o[e] = (short)T[8*(8*dg + e) + h][16*tl + lli];
      *(s16x8*)&dst[((((size_t)(n*NH + h))*64 + (tok0 >> 4) + tl)*2 + ks)*512 + L*8] = o;
    }
  };

  if (z == 0) {
    fillT(false); __syncthreads(); scatterF(qht);
    __syncthreads();
    fillT(true);  __syncthreads(); scatterF(qlt);
  } else if (z == 1) {
    fillT(false); __syncthreads(); scatterF(kf_);
  } else {
    fillT(false); __syncthreads();
    const int j0 = d0 >> 4;
    #pragma unroll
    for (int it = 0; it < 8; it++) {
      const int chunk = tid + 256*it;
      const int h   = chunk >> 8;
      const int rem = chunk & 255;
      const int sl  = rem >> 6;             // 0..3 local 32-tok group
      const int L   = rem & 63;
      const int gg  = L >> 4, lli = L & 15;
      s16x8 o = *(const s16x8*)&T[8*lli + h][32*sl + 8*gg];
      *(s16x8*)&vf_[((((size_t)(n*NH + h))*32 + (tok0 >> 5) + sl)*4 + j0)*512 + L*8] = o;
    }
  }
}

// ---------------- fused attention: LDS-shared K/V, 8 waves = 128 q of one head ----------------
__global__ __launch_bounds__(512, 4)
void attn_fused(const u16* __restrict__ qhf_g, const u16* __restrict__ qlf_g,
                const u16* __restrict__ kf_g, const u16* __restrict__ vf_g,
                u16* __restrict__ pg, float* __restrict__ rg,
                float* __restrict__ cs_g)
{
  __shared__ __align__(16) u16 Klds[2][4096];     // 16 KB
  __shared__ __align__(16) u16 Vlds[2][4096];     // 16 KB
  __shared__ __align__(16) float Pb[8][16][68];   // 34816 B

  const int tid  = threadIdx.x;
  const int wid  = tid >> 6, lane = tid & 63;
  const int g    = lane >> 4, li  = lane & 15;
  const int bid  = blockIdx.x;
  const int n    = bid >> 6;
  const int h    = (bid >> 3) & 7;
  const int qb   = bid & 7;
  const int tq   = qb*8 + wid;                    // q-tile (16 rows) 0..63

  const float SC2 = 0.18033688011112042f;         // (1/8)*log2(e)

  // Q fragments: dense 1KB/wave
  s16x8 qhf[2], qlf[2];
  {
    const size_t qoff = (((size_t)(n*NH + h))*64 + tq)*1024 + (size_t)lane*8;
    qhf[0] = *(const s16x8*)(qhf_g + qoff);
    qhf[1] = *(const s16x8*)(qhf_g + qoff + 512);
    qlf[0] = *(const s16x8*)(qlf_g + qoff);
    qlf[1] = *(const s16x8*)(qlf_g + qoff + 512);
  }

  const u16* Kt = kf_g + ((size_t)(n*NH + h))*65536;   // 128 KB/head
  const u16* Vt = vf_g + ((size_t)(n*NH + h))*65536;

  s16x8 sk, sv;
  auto issue = [&](int step) {
    sk = *(const s16x8*)(Kt + (size_t)step*4096 + tid*8);
    sv = *(const s16x8*)(Vt + (size_t)step*4096 + tid*8);
  };
  auto commit = [&](int buf) {
    *(s16x8*)&Klds[buf][tid*8] = sk;
    *(s16x8*)&Vlds[buf][tid*8] = sv;
  };

  float l_[4] = {0.f, 0.f, 0.f, 0.f};
  f32x4 ctx[4];
  #pragma unroll
  for (int j = 0; j < 4; j++) ctx[j] = f32x4{0.f, 0.f, 0.f, 0.f};

  u16* prow = pg + (((size_t)(n*NH + h))*64 + tq)*16384;   // [k][qi16]
  const int kl = lane >> 1;          // 0..31
  const int qo = (lane & 1) * 8;     // 0/8

  issue(0); commit(0);
  __syncthreads();

  for (int step = 0; step < 16; ++step) {
    const int buf = step & 1;
    if (step < 15) issue(step + 1);          // loads in flight during compute (T14)

    // ---- QK^T over 64 tokens ----
    #pragma unroll
    for (int tloc = 0; tloc < 4; tloc++) {
      s16x8 kf0 = *(const s16x8*)&Klds[buf][(tloc*2 + 0)*512 + lane*8];
      s16x8 kf1 = *(const s16x8*)&Klds[buf][(tloc*2 + 1)*512 + lane*8];
      f32x4 a = f32x4{0.f,0.f,0.f,0.f}, c = f32x4{0.f,0.f,0.f,0.f};
      a = __builtin_amdgcn_mfma_f32_16x16x32_bf16(qhf[0], kf0, a, 0, 0, 0);
      a = __builtin_amdgcn_mfma_f32_16x16x32_bf16(qhf[1], kf1, a, 0, 0, 0);
      c = __builtin_amdgcn_mfma_f32_16x16x32_bf16(qlf[0], kf0, c, 0, 0, 0);
      c = __builtin_amdgcn_mfma_f32_16x16x32_bf16(qlf[1], kf1, c, 0, 0, 0);
      #pragma unroll
      for (int r = 0; r < 4; r++) {
        float P = __builtin_exp2f((a[r] + c[r]) * SC2);
        l_[r] += P;
        Pb[wid][4*g + r][16*tloc + li] = P;
      }
    }

    // ---- p-store (dense tile-linear) + PV ----
    #pragma unroll
    for (int kc = 0; kc < 2; kc++) {
      s16x8 ps;
      #pragma unroll
      for (int e = 0; e < 8; e++)
        ps[e] = (short)bf16_of(Pb[wid][qo + e][kc*32 + kl]);
      *(s16x8*)(prow + (size_t)(step*64 + kc*32 + kl)*16 + qo) = ps;

      f32x4 p0 = *(const f32x4*)&Pb[wid][li][kc*32 + 8*g];
      f32x4 p1 = *(const f32x4*)&Pb[wid][li][kc*32 + 8*g + 4];
      s16x8 pa;
      #pragma unroll
      for (int e = 0; e < 4; e++) { pa[e] = (short)bf16_of(p0[e]); pa[e+4] = (short)bf16_of(p1[e]); }
      #pragma unroll
      for (int j = 0; j < 4; j++) {
        s16x8 vfj = *(const s16x8*)&Vlds[buf][(kc*4 + j)*512 + lane*8];
        ctx[j] = __builtin_amdgcn_mfma_f32_16x16x32_bf16(pa, vfj, ctx[j], 0, 0, 0);
      }
    }

    __syncthreads();
    if (step < 15) commit(buf ^ 1);
    __syncthreads();
  }

  // ---- l reduce over 16 col-lanes; store rinv; scale+store ctx (dense per-head scratch) ----
  float rinv[4];
  #pragma unroll
  for (int r = 0; r < 4; r++) {
    float l = l_[r];
    #pragma unroll
    for (int off = 1; off < 16; off <<= 1)
      l += __shfl_xor(l, off, 64);
    rinv[r] = 1.0f / l;
  }
  if (li == 0) {
    #pragma unroll
    for (int r = 0; r < 4; r++)
      rg[((size_t)(n*NH + h))*SEQ + tq*16 + 4*g + r] = rinv[r];
  }
  float* csb = cs_g + (((size_t)(n*NH + h))*64 + tq)*1024;
  #pragma unroll
  for (int j = 0; j < 4; j++)
    #pragma unroll
    for (int r = 0; r < 4; r++)
      csb[(4*g + r)*64 + 16*j + li] = ctx[j][r] * rinv[r];
}

// ---------------- streaming normalize + gather: p->attn, cs->ctx ----------------
__global__ __launch_bounds__(256, 4)
void norm_kernel(const u16* __restrict__ pg, const float* __restrict__ rg,
                 const float* __restrict__ cs, float* __restrict__ ctx_out,
                 float* __restrict__ attn_out)
{
  __shared__ float rv[NH][16];
  const int tid = threadIdx.x;
  const int b   = blockIdx.x;          // NB*64
  const int n   = b >> 6;
  const int qt  = b & 63;
  const int q0  = qt * 16;

  if (tid < 128)
    rv[tid >> 4][tid & 15] = rg[((size_t)(n*NH + (tid >> 4)))*SEQ + q0 + (tid & 15)];
  __syncthreads();

  // ---- ctx merge: thread -> (q, 32-float output chunk) ----
  {
    const int q  = tid >> 4;           // 0..15
    const int dg = tid & 15;           // 0..15
    const float* csb = cs + (((size_t)(n*NH))*64 + qt)*1024 + q*64 + dg*4;
    float* crow = ctx_out + ((size_t)(n*SEQ + q0 + q))*CIN + dg*32;
    #pragma unroll
    for (int dd = 0; dd < 4; dd++) {
      f32x4 lo, hi;
      #pragma unroll
      for (int hh = 0; hh < 4; hh++) {
        lo[hh] = csb[(size_t)hh*65536 + dd];
        hi[hh] = csb[(size_t)(hh+4)*65536 + dd];
      }
      *(f32x4*)(crow + dd*8)     = lo;
      *(f32x4*)(crow + dd*8 + 4) = hi;
    }
  }

  // ---- p normalize: [n][h][qt][k][qi] -> attn [q][k][h] ----
  for (int it = 0; it < 4; ++it) {
    const int k = it*256 + tid;
    s16x8 c[NH][2];
    #pragma unroll
    for (int hh = 0; hh < NH; hh++) {
      const u16* src = pg + (((size_t)(n*NH + hh))*64 + qt)*16384 + (size_t)k*16;
      c[hh][0] = *(const s16x8*)(src);
      c[hh][1] = *(const s16x8*)(src + 8);
    }
    float* dst = attn_out + ((size_t)(n*SEQ + q0)*SEQ + k)*NH;
    #pragma unroll
    for (int qi = 0; qi < 16; qi++) {
      f32x4 lo, hi;
      #pragma unroll
      for (int hh = 0; hh < 4; hh++) {
        lo[hh] = f32_of((u16)c[hh][qi >> 3][qi & 7])   * rv[hh][qi];
        hi[hh] = f32_of((u16)c[hh+4][qi >> 3][qi & 7]) * rv[hh+4][qi];
      }
      *(f32x4*)(dst + (size_t)qi*SEQ*NH)     = lo;
      *(f32x4*)(dst + (size_t)qi*SEQ*NH + 4) = hi;
    }
  }
}

// ---------------- launch ----------------
extern "C" void kernel_launch(void* const* d_in, const int* in_sizes, int n_in,
                              void* d_out, int out_size, void* d_ws, size_t ws_size,
                              hipStream_t stream) {
  const float* x  = (const float*)d_in[0];
  const float* wq = (const float*)d_in[1];
  const float* bq = (const float*)d_in[2];
  const float* wk = (const float*)d_in[3];
  const float* bk = (const float*)d_in[4];
  const float* wv = (const float*)d_in[5];
  const float* bv = (const float*)d_in[6];

  float* ctx_out  = (float*)d_out;
  float* attn_out = ctx_out + (size_t)NB * SEQ * CIN;

  const size_t qkv_elems = (size_t)MROWS * CIN;     // 4M u16 each
  u16* qht = (u16*)d_ws;
  u16* qlt = qht + qkv_elems;
  u16* kf  = qlt + qkv_elems;
  u16* vf  = kf  + qkv_elems;
  u16* pgm = vf  + qkv_elems;                               // 64M u16 = 128 MB
  float* rg = (float*)(pgm + (size_t)NB*NH*SEQ*SEQ);        // 256 KB
  float* cs = rg + (size_t)NB*NH*SEQ;                       // 16 MB

  dim3 pg_(MROWS / BM, CIN / BN, 3);
  proj_kernel<<<pg_, 256, 0, stream>>>(x, wq, bq, wk, bk, wv, bv, qht, qlt, kf, vf);

  attn_fused<<<dim3(NB * NH * 8), 512, 0, stream>>>(qht, qlt, kf, vf, pgm, rg, cs);

  norm_kernel<<<dim3(NB * 64), 256, 0, stream>>>(pgm, rg, cs, ctx_out, attn_out);
}

// Round 9
// 208.633 us; speedup vs baseline: 1.5424x; 1.1861x over previous
//
#include <hip/hip_runtime.h>

typedef float f32x4 __attribute__((ext_vector_type(4)));
typedef short s16x8 __attribute__((ext_vector_type(8)));
typedef unsigned short u16;

#define NB 8
#define SEQ 1024
#define CIN 512
#define NH 8
#define DK 64
#define MROWS (NB*SEQ)

__device__ __forceinline__ u16 bf16_of(float f) {
  unsigned u = __builtin_bit_cast(unsigned, f);
  u += 0x7fffu + ((u >> 16) & 1u);           // RTNE
  return (u16)(u >> 16);
}
__device__ __forceinline__ float f32_of(u16 b) {
  unsigned u = ((unsigned)b) << 16;
  return __builtin_bit_cast(float, u);
}

// async global->LDS, 16B per lane: LDS dest = (wave-uniform base) + lane*16
__device__ __forceinline__ void gload16(const u16* g, u16* l) {
  __builtin_amdgcn_global_load_lds(
      (const __attribute__((address_space(1))) void*)(g),
      (__attribute__((address_space(3))) void*)(l), 16, 0, 0);
}

// ================= layouts (fragment-linear, u16) =================
// QF/KF: [n][h][t16(64)][ks(2)][lane(64)*8]
// VF:    [n][h][s32(32)][j(4)][lane(64)*8]
// pg:    [n][h][qt(64)][k(1024)][qi(16)]  bf16 unnormalized
// rg:    [n][h][q] f32 rinv
// cs:    [n][h][qt(64)][qi(16)][d(64)] f32 ctx (pre-scaled)

// ---------------- QKV projection (bf16 MFMA, X split hi/lo) ----------------
#define BM 128
#define BN 128
#define BK 32
#define LDP 40
#define TP  136

__global__ __launch_bounds__(256, 2)
void proj_kernel(const float* __restrict__ x,
                 const float* __restrict__ wq, const float* __restrict__ bq,
                 const float* __restrict__ wk, const float* __restrict__ bk,
                 const float* __restrict__ wv, const float* __restrict__ bv,
                 u16* __restrict__ qht, u16* __restrict__ qlt,
                 u16* __restrict__ kf_, u16* __restrict__ vf_)
{
  __shared__ __align__(16) u16 smem[128 * TP];
  u16 (*Ah)[LDP] = (u16(*)[LDP])(smem);
  u16 (*Al)[LDP] = (u16(*)[LDP])(smem + 128*LDP);
  u16 (*Bw)[LDP] = (u16(*)[LDP])(smem + 256*LDP);

  const int tid  = threadIdx.x;
  const int wid  = tid >> 6, lane = tid & 63;
  const int g    = lane >> 4, li  = lane & 15;
  const int m0   = blockIdx.x * BM;
  const int n0   = blockIdx.y * BN;
  const int z    = blockIdx.z;

  const float* w    = (z == 0) ? wq : (z == 1) ? wk : wv;
  const float* bias = (z == 0) ? bq : (z == 1) ? bk : bv;

  const int wm = wid >> 1, wn = wid & 1;

  f32x4 acc[4][4];
  #pragma unroll
  for (int i = 0; i < 4; i++)
    #pragma unroll
    for (int j = 0; j < 4; j++)
      acc[i][j] = f32x4{0.f, 0.f, 0.f, 0.f};

  const int srow  = tid >> 1;
  const int shalf = (tid & 1) * 16;

  for (int k0 = 0; k0 < CIN; k0 += BK) {
    __syncthreads();
    {
      const float* ax = x + (size_t)(m0 + srow) * CIN + k0 + shalf;
      #pragma unroll
      for (int e = 0; e < 16; e++) {
        float v = ax[e];
        u16 h = bf16_of(v);
        Ah[srow][shalf + e] = h;
        Al[srow][shalf + e] = bf16_of(v - f32_of(h));
      }
      const float* bx = w + (size_t)(n0 + srow) * CIN + k0 + shalf;
      #pragma unroll
      for (int e = 0; e < 16; e++)
        Bw[srow][shalf + e] = bf16_of(bx[e]);
    }
    __syncthreads();

    s16x8 af[4], alf[4], bfr[4];
    #pragma unroll
    for (int i = 0; i < 4; i++) {
      af[i]  = *(const s16x8*)&Ah[wm*64 + i*16 + li][8*g];
      alf[i] = *(const s16x8*)&Al[wm*64 + i*16 + li][8*g];
      bfr[i] = *(const s16x8*)&Bw[wn*64 + i*16 + li][8*g];
    }
    #pragma unroll
    for (int i = 0; i < 4; i++)
      #pragma unroll
      for (int j = 0; j < 4; j++) {
        acc[i][j] = __builtin_amdgcn_mfma_f32_16x16x32_bf16(af[i],  bfr[j], acc[i][j], 0, 0, 0);
        acc[i][j] = __builtin_amdgcn_mfma_f32_16x16x32_bf16(alf[i], bfr[j], acc[i][j], 0, 0, 0);
      }
  }

  // ---- epilogues: T[c_local][r_local] then fragment-linear scatter ----
  __syncthreads();
  u16 (*T)[TP] = (u16(*)[TP])smem;
  const int n    = m0 >> 10;
  const int tok0 = m0 & 1023;
  const int d0   = n0 >> 3;

  auto fillT = [&](bool lo) {
    #pragma unroll
    for (int j = 0; j < 4; j++) {
      const int cl = wn*64 + j*16 + li;
      const float bv_ = bias[n0 + cl];
      #pragma unroll
      for (int i = 0; i < 4; i++) {
        const int rbase = wm*64 + i*16 + 4*g;
        #pragma unroll
        for (int r = 0; r < 4; r++) {
          float y = acc[i][j][r] + bv_;
          u16 hi = bf16_of(y);
          T[cl][rbase + r] = lo ? bf16_of(y - f32_of(hi)) : hi;
        }
      }
    }
  };

  auto scatterF = [&](u16* __restrict__ dst) {
    const int ks = d0 >> 5;
    const int g0 = (d0 & 31) >> 3;
    #pragma unroll
    for (int it = 0; it < 8; it++) {
      const int chunk = tid + 256*it;
      const int h   = chunk >> 8;
      const int rem = chunk & 255;
      const int tl  = rem >> 5;
      const int Lo  = rem & 31;
      const int L   = 16*g0 + Lo;
      const int dg  = Lo >> 4;
      const int lli = L & 15;
      s16x8 o;
      #pragma unroll
      for (int e = 0; e < 8; e++)
        o[e] = (short)T[8*(8*dg + e) + h][16*tl + lli];
      *(s16x8*)&dst[((((size_t)(n*NH + h))*64 + (tok0 >> 4) + tl)*2 + ks)*512 + L*8] = o;
    }
  };

  if (z == 0) {
    fillT(false); __syncthreads(); scatterF(qht);
    __syncthreads();
    fillT(true);  __syncthreads(); scatterF(qlt);
  } else if (z == 1) {
    fillT(false); __syncthreads(); scatterF(kf_);
  } else {
    fillT(false); __syncthreads();
    const int j0 = d0 >> 4;
    #pragma unroll
    for (int it = 0; it < 8; it++) {
      const int chunk = tid + 256*it;
      const int h   = chunk >> 8;
      const int rem = chunk & 255;
      const int sl  = rem >> 6;
      const int L   = rem & 63;
      const int gg  = L >> 4, lli = L & 15;
      s16x8 o = *(const s16x8*)&T[8*lli + h][32*sl + 8*gg];
      *(s16x8*)&vf_[((((size_t)(n*NH + h))*32 + (tok0 >> 5) + sl)*4 + j0)*512 + L*8] = o;
    }
  }
}

// ---------------- fused attention: gload_lds K/V, 1 barrier/step ----------------
__global__ __launch_bounds__(512, 2)
void attn_fused(const u16* __restrict__ qhf_g, const u16* __restrict__ qlf_g,
                const u16* __restrict__ kf_g, const u16* __restrict__ vf_g,
                u16* __restrict__ pg, float* __restrict__ rg,
                float* __restrict__ cs_g)
{
  __shared__ __align__(16) u16 Klds0[4096], Klds1[4096];   // 8 KB each
  __shared__ __align__(16) u16 Vlds0[4096], Vlds1[4096];
  __shared__ __align__(16) float Pb[8][16][68];            // 34816 B

  const int tid  = threadIdx.x;
  const int wid  = tid >> 6, lane = tid & 63;
  const int g    = lane >> 4, li  = lane & 15;
  const int bid  = blockIdx.x;
  const int n    = bid >> 6;
  const int h    = (bid >> 3) & 7;
  const int qb   = bid & 7;
  const int tq   = qb*8 + wid;                    // q-tile (16 rows) 0..63

  const float SC2 = 0.18033688011112042f;         // (1/8)*log2(e)

  s16x8 qhf[2], qlf[2];
  {
    const size_t qoff = (((size_t)(n*NH + h))*64 + tq)*1024 + (size_t)lane*8;
    qhf[0] = *(const s16x8*)(qhf_g + qoff);
    qhf[1] = *(const s16x8*)(qhf_g + qoff + 512);
    qlf[0] = *(const s16x8*)(qlf_g + qoff);
    qlf[1] = *(const s16x8*)(qlf_g + qoff + 512);
  }

  const u16* Kt = kf_g + ((size_t)(n*NH + h))*65536;
  const u16* Vt = vf_g + ((size_t)(n*NH + h))*65536;
  const int soff = wid*512 + lane*8;              // element offset in step tile

  auto stage = [&](int step, u16* kd, u16* vd) {
    gload16(Kt + (size_t)step*4096 + soff, kd + wid*512);
    gload16(Vt + (size_t)step*4096 + soff, vd + wid*512);
  };

  float l_[4] = {0.f, 0.f, 0.f, 0.f};
  f32x4 ctx[4];
  #pragma unroll
  for (int j = 0; j < 4; j++) ctx[j] = f32x4{0.f, 0.f, 0.f, 0.f};

  u16* prow = pg + (((size_t)(n*NH + h))*64 + tq)*16384;   // [k][qi16]
  const int kl = lane >> 1;
  const int qo = (lane & 1) * 8;

  auto compute = [&](int step, const u16* kb, const u16* vb) {
    // ---- QK^T over 64 tokens ----
    #pragma unroll
    for (int tloc = 0; tloc < 4; tloc++) {
      s16x8 kf0 = *(const s16x8*)(kb + (tloc*2 + 0)*512 + lane*8);
      s16x8 kf1 = *(const s16x8*)(kb + (tloc*2 + 1)*512 + lane*8);
      f32x4 a = f32x4{0.f,0.f,0.f,0.f}, c = f32x4{0.f,0.f,0.f,0.f};
      a = __builtin_amdgcn_mfma_f32_16x16x32_bf16(qhf[0], kf0, a, 0, 0, 0);
      a = __builtin_amdgcn_mfma_f32_16x16x32_bf16(qhf[1], kf1, a, 0, 0, 0);
      c = __builtin_amdgcn_mfma_f32_16x16x32_bf16(qlf[0], kf0, c, 0, 0, 0);
      c = __builtin_amdgcn_mfma_f32_16x16x32_bf16(qlf[1], kf1, c, 0, 0, 0);
      #pragma unroll
      for (int r = 0; r < 4; r++) {
        float P = __builtin_exp2f((a[r] + c[r]) * SC2);
        l_[r] += P;
        Pb[wid][4*g + r][16*tloc + li] = P;
      }
    }
    // ---- p-store (dense tile-linear) + PV ----
    #pragma unroll
    for (int kc = 0; kc < 2; kc++) {
      s16x8 ps;
      #pragma unroll
      for (int e = 0; e < 8; e++)
        ps[e] = (short)bf16_of(Pb[wid][qo + e][kc*32 + kl]);
      *(s16x8*)(prow + (size_t)(step*64 + kc*32 + kl)*16 + qo) = ps;

      f32x4 p0 = *(const f32x4*)&Pb[wid][li][kc*32 + 8*g];
      f32x4 p1 = *(const f32x4*)&Pb[wid][li][kc*32 + 8*g + 4];
      s16x8 pa;
      #pragma unroll
      for (int e = 0; e < 4; e++) { pa[e] = (short)bf16_of(p0[e]); pa[e+4] = (short)bf16_of(p1[e]); }
      #pragma unroll
      for (int j = 0; j < 4; j++) {
        s16x8 vfj = *(const s16x8*)(vb + (kc*4 + j)*512 + lane*8);
        ctx[j] = __builtin_amdgcn_mfma_f32_16x16x32_bf16(pa, vfj, ctx[j], 0, 0, 0);
      }
    }
  };

  stage(0, Klds0, Vlds0);
  __syncthreads();                                 // drains vmcnt -> buf0 ready

  for (int s2 = 0; s2 < 8; ++s2) {
    const int sE = 2*s2, sO = 2*s2 + 1;
    stage(sO, Klds1, Vlds1);                       // in flight under compute
    compute(sE, Klds0, Vlds0);
    __syncthreads();                               // buf1 ready; buf0 free
    if (s2 < 7) stage(sE + 2, Klds0, Vlds0);
    compute(sO, Klds1, Vlds1);
    __syncthreads();
  }

  // ---- l reduce; rinv; scaled ctx to per-head scratch ----
  float rinv[4];
  #pragma unroll
  for (int r = 0; r < 4; r++) {
    float l = l_[r];
    #pragma unroll
    for (int off = 1; off < 16; off <<= 1)
      l += __shfl_xor(l, off, 64);
    rinv[r] = 1.0f / l;
  }
  if (li == 0) {
    #pragma unroll
    for (int r = 0; r < 4; r++)
      rg[((size_t)(n*NH + h))*SEQ + tq*16 + 4*g + r] = rinv[r];
  }
  float* csb = cs_g + (((size_t)(n*NH + h))*64 + tq)*1024;
  #pragma unroll
  for (int j = 0; j < 4; j++)
    #pragma unroll
    for (int r = 0; r < 4; r++)
      csb[(4*g + r)*64 + 16*j + li] = ctx[j][r] * rinv[r];
}

// ---------------- streaming normalize + gather (2048 blocks) ----------------
__global__ __launch_bounds__(256, 4)
void norm_kernel(const u16* __restrict__ pg, const float* __restrict__ rg,
                 const float* __restrict__ cs, float* __restrict__ ctx_out,
                 float* __restrict__ attn_out)
{
  __shared__ float rv[NH][16];
  const int tid = threadIdx.x;
  const int b   = blockIdx.x;          // NB*64*4
  const int n   = b >> 8;
  const int qt  = (b >> 2) & 63;
  const int kc  = b & 3;
  const int q0  = qt * 16;

  if (tid < 128)
    rv[tid >> 4][tid & 15] = rg[((size_t)(n*NH + (tid >> 4)))*SEQ + q0 + (tid & 15)];
  __syncthreads();

  // ---- p normalize: [n][h][qt][k][qi] -> attn [q][k][h] ----
  {
    const int k = kc*256 + tid;
    s16x8 c[NH][2];
    #pragma unroll
    for (int hh = 0; hh < NH; hh++) {
      const u16* src = pg + (((size_t)(n*NH + hh))*64 + qt)*16384 + (size_t)k*16;
      c[hh][0] = *(const s16x8*)(src);
      c[hh][1] = *(const s16x8*)(src + 8);
    }
    float* dst = attn_out + ((size_t)(n*SEQ + q0)*SEQ + k)*NH;
    #pragma unroll
    for (int qi = 0; qi < 16; qi++) {
      f32x4 lo, hi;
      #pragma unroll
      for (int hh = 0; hh < 4; hh++) {
        lo[hh] = f32_of((u16)c[hh][qi >> 3][qi & 7])   * rv[hh][qi];
        hi[hh] = f32_of((u16)c[hh+4][qi >> 3][qi & 7]) * rv[hh+4][qi];
      }
      *(f32x4*)(dst + (size_t)qi*SEQ*NH)     = lo;
      *(f32x4*)(dst + (size_t)qi*SEQ*NH + 4) = hi;
    }
  }

  // ---- ctx merge on kc==0 blocks ----
  if (kc == 0) {
    const int q  = tid >> 4;
    const int dg = tid & 15;
    const float* csb = cs + (((size_t)(n*NH))*64 + qt)*1024 + q*64 + dg*4;
    float* crow = ctx_out + ((size_t)(n*SEQ + q0 + q))*CIN + dg*32;
    #pragma unroll
    for (int dd = 0; dd < 4; dd++) {
      f32x4 lo, hi;
      #pragma unroll
      for (int hh = 0; hh < 4; hh++) {
        lo[hh] = csb[(size_t)hh*65536 + dd];
        hi[hh] = csb[(size_t)(hh+4)*65536 + dd];
      }
      *(f32x4*)(crow + dd*8)     = lo;
      *(f32x4*)(crow + dd*8 + 4) = hi;
    }
  }
}

// ---------------- launch ----------------
extern "C" void kernel_launch(void* const* d_in, const int* in_sizes, int n_in,
                              void* d_out, int out_size, void* d_ws, size_t ws_size,
                              hipStream_t stream) {
  const float* x  = (const float*)d_in[0];
  const float* wq = (const float*)d_in[1];
  const float* bq = (const float*)d_in[2];
  const float* wk = (const float*)d_in[3];
  const float* bk = (const float*)d_in[4];
  const float* wv = (const float*)d_in[5];
  const float* bv = (const float*)d_in[6];

  float* ctx_out  = (float*)d_out;
  float* attn_out = ctx_out + (size_t)NB * SEQ * CIN;

  const size_t qkv_elems = (size_t)MROWS * CIN;
  u16* qht = (u16*)d_ws;
  u16* qlt = qht + qkv_elems;
  u16* kf  = qlt + qkv_elems;
  u16* vf  = kf  + qkv_elems;
  u16* pgm = vf  + qkv_elems;                               // 128 MB
  float* rg = (float*)(pgm + (size_t)NB*NH*SEQ*SEQ);        // 256 KB
  float* cs = rg + (size_t)NB*NH*SEQ;                       // 16 MB

  dim3 pg_(MROWS / BM, CIN / BN, 3);
  proj_kernel<<<pg_, 256, 0, stream>>>(x, wq, bq, wk, bk, wv, bv, qht, qlt, kf, vf);

  attn_fused<<<dim3(NB * NH * 8), 512, 0, stream>>>(qht, qlt, kf, vf, pgm, rg, cs);

  norm_kernel<<<dim3(NB * 64 * 4), 256, 0, stream>>>(pgm, rg, cs, ctx_out, attn_out);
}